// Round 1
// 1223.305 us; speedup vs baseline: 1.4180x; 1.4180x over previous
//
#include <hip/hip_runtime.h>
#include <hip/hip_bf16.h>
#include <math.h>

// Qwen3 MoE sparse block: router (top-8 of 64) + grouped SwiGLU experts.
// H=2048, I=768, E=64, K=8, T=1024. All inputs fp32; compute in bf16 MFMA.
//
// v2: latency-bound fix. Both GEMMs restructured:
//   - finer output chunks (64 I / 64 H) -> 768 / 2048 live blocks (3 / 8 per CU)
//   - BK=32, double-buffered LDS, ONE barrier per k-step
//   - reg-staged prefetch: next k-slab's global loads issued right AFTER the
//     barrier, so HBM latency hides under ds_read+MFMA and every __syncthreads
//     executes with zero outstanding vmem loads (drain is free).
//
// ws layout:
//   zbuf  : bf16[8192][768]   slot = t*8 + k          (12,582,912 B)
//   cnt   : int[64]                                    (256 B, padded)
//   elist : int[64][1024]     entry = (t<<3)|k         (262,144 B)
//   ewt   : float[64][1024]   renormalized routing wt  (262,144 B)

#define HIDDEN 2048
#define INTER  768
#define NEXP   64
#define TOPK   8
#define NTOK   1024
#define CAP    1024
#define LDA    40   // padded LDS row stride (bf16 elems): 80 B = 5*16 B

typedef __bf16 bf16x4 __attribute__((ext_vector_type(4)));
typedef __bf16 bf16x8 __attribute__((ext_vector_type(8)));
typedef float  f32x4  __attribute__((ext_vector_type(4)));

// ---------------- Router: one wave per token, lane = expert ----------------
__global__ __launch_bounds__(64) void router_kernel(
    const float* __restrict__ x, const float* __restrict__ gw,
    int* __restrict__ cnt, int* __restrict__ elist, float* __restrict__ ewt)
{
  const int t = blockIdx.x;
  const int lane = threadIdx.x;
  const float* xr = x + (size_t)t * HIDDEN;
  const float* gr = gw + (size_t)lane * HIDDEN;

  float acc = 0.f;
  for (int h = 0; h < HIDDEN; h += 4) {
    float4 xv = *(const float4*)(xr + h);
    float4 gv = *(const float4*)(gr + h);
    acc += xv.x * gv.x + xv.y * gv.y + xv.z * gv.z + xv.w * gv.w;
  }

  // top-8 by repeated wave argmax; tie-break lower index (matches jax top_k)
  float v = acc;
  float topv[TOPK];
  int   topi[TOPK];
  #pragma unroll
  for (int k = 0; k < TOPK; ++k) {
    float mv = v; int mi = lane;
    #pragma unroll
    for (int off = 32; off > 0; off >>= 1) {
      float ov = __shfl_xor(mv, off);
      int   oi = __shfl_xor(mi, off);
      if (ov > mv || (ov == mv && oi < mi)) { mv = ov; mi = oi; }
    }
    topv[k] = mv; topi[k] = mi;
    if (lane == mi) v = -INFINITY;
  }

  // softmax over top-8 == softmax-then-renormalize of the reference
  const float m = topv[0];
  float w[TOPK], sum = 0.f;
  #pragma unroll
  for (int k = 0; k < TOPK; ++k) { w[k] = __expf(topv[k] - m); sum += w[k]; }
  const float inv = 1.f / sum;

  if (lane < TOPK) {
    const int e = topi[lane];
    const int pos = atomicAdd(&cnt[e], 1);
    elist[e * CAP + pos] = (t << 3) | lane;
    ewt[e * CAP + pos]   = w[lane] * inv;
  }
}

// ------------- Gate+Up: z = silu(x@Wg^T) * (x@Wu^T) * wt, bf16 -------------
// grid: (expert, token-tile/128, I-chunk/64), block 256 = 4 waves (2x2)
// tile: 128 tokens x 64 I, BK=32, dbuf LDS, 1 barrier per k-step
__global__ __launch_bounds__(256, 3) void gateup_kernel(
    const float* __restrict__ x, const float* __restrict__ Wg,
    const float* __restrict__ Wu, const int* __restrict__ cnt,
    const int* __restrict__ elist, const float* __restrict__ ewt,
    __bf16* __restrict__ zbuf)
{
  const int e = blockIdx.x;
  const int n_e = cnt[e];
  const int row0 = blockIdx.y * 128;
  if (row0 >= n_e) return;
  const int nrows = min(128, n_e - row0);
  const int ic0 = blockIdx.z * 64;

  __shared__ __bf16 As[2][128 * LDA];
  __shared__ __bf16 Gs[2][64 * LDA];
  __shared__ __bf16 Us[2][64 * LDA];
  __shared__ int   s_slot[128];
  __shared__ float s_wt[128];

  const int tid = threadIdx.x;
  if (tid < 128) {
    // clamp tail rows to the last valid slot: staged data is a duplicate row,
    // results for r >= nrows are discarded by the epilogue guard.
    s_slot[tid] = elist[e * CAP + row0 + min(tid, nrows - 1)];
    s_wt[tid]   = (tid < nrows) ? ewt[e * CAP + row0 + tid] : 0.f;
  }
  __syncthreads();

  // staging geometry: 8 threads per 32-float row segment
  const int srow = tid >> 3;          // 0..31
  const int scol = (tid & 7) * 4;     // 0..28, float4 granularity

  const float* ap[4];
  #pragma unroll
  for (int i = 0; i < 4; ++i)
    ap[i] = x + (size_t)(s_slot[srow + 32 * i] >> 3) * HIDDEN + scol;
  const float* gp0 = Wg + ((size_t)e * INTER + ic0 + srow) * HIDDEN + scol;
  const float* gp1 = gp0 + (size_t)32 * HIDDEN;
  const float* up0 = Wu + ((size_t)e * INTER + ic0 + srow) * HIDDEN + scol;
  const float* up1 = up0 + (size_t)32 * HIDDEN;

  const int wave = tid >> 6, lane = tid & 63;
  const int wm = wave >> 1, wn = wave & 1;
  const int lq = lane >> 4, lr = lane & 15;

  f32x4 accg[8], accu[8];
  #pragma unroll
  for (int i = 0; i < 8; ++i) {
    accg[i] = (f32x4){0.f, 0.f, 0.f, 0.f};
    accu[i] = (f32x4){0.f, 0.f, 0.f, 0.f};
  }

  float4 rA[4], rG[2], rU[2];
  // prologue: issue k-slab 0
  #pragma unroll
  for (int i = 0; i < 4; ++i) rA[i] = *(const float4*)(ap[i]);
  rG[0] = *(const float4*)(gp0); rG[1] = *(const float4*)(gp1);
  rU[0] = *(const float4*)(up0); rU[1] = *(const float4*)(up1);

  #pragma unroll 2
  for (int kt = 0; kt < 64; ++kt) {
    __bf16* as = As[kt & 1];
    __bf16* gs = Gs[kt & 1];
    __bf16* us = Us[kt & 1];

    // WRITE: cvt staged regs -> bf16 LDS (vmcnt waits happen here, pre-barrier)
    #pragma unroll
    for (int i = 0; i < 4; ++i) {
      bf16x4 b = { (__bf16)rA[i].x, (__bf16)rA[i].y, (__bf16)rA[i].z, (__bf16)rA[i].w };
      *(bf16x4*)(as + (srow + 32 * i) * LDA + scol) = b;
    }
    {
      bf16x4 b0 = { (__bf16)rG[0].x, (__bf16)rG[0].y, (__bf16)rG[0].z, (__bf16)rG[0].w };
      *(bf16x4*)(gs + srow * LDA + scol) = b0;
      bf16x4 b1 = { (__bf16)rG[1].x, (__bf16)rG[1].y, (__bf16)rG[1].z, (__bf16)rG[1].w };
      *(bf16x4*)(gs + (srow + 32) * LDA + scol) = b1;
      bf16x4 c0 = { (__bf16)rU[0].x, (__bf16)rU[0].y, (__bf16)rU[0].z, (__bf16)rU[0].w };
      *(bf16x4*)(us + srow * LDA + scol) = c0;
      bf16x4 c1 = { (__bf16)rU[1].x, (__bf16)rU[1].y, (__bf16)rU[1].z, (__bf16)rU[1].w };
      *(bf16x4*)(us + (srow + 32) * LDA + scol) = c1;
    }
    __syncthreads();   // zero vmem loads outstanding here -> drain is free

    // ISSUE next k-slab: flies under ds_read + MFMA below
    if (kt < 63) {
      const int k0 = (kt + 1) * 32;
      #pragma unroll
      for (int i = 0; i < 4; ++i) rA[i] = *(const float4*)(ap[i] + k0);
      rG[0] = *(const float4*)(gp0 + k0); rG[1] = *(const float4*)(gp1 + k0);
      rU[0] = *(const float4*)(up0 + k0); rU[1] = *(const float4*)(up1 + k0);
    }

    // COMPUTE current buffer
    bf16x8 a[4], bg[2], bu[2];
    #pragma unroll
    for (int mi = 0; mi < 4; ++mi)
      a[mi] = *(const bf16x8*)(as + (wm * 64 + mi * 16 + lr) * LDA + lq * 8);
    #pragma unroll
    for (int ni = 0; ni < 2; ++ni) {
      bg[ni] = *(const bf16x8*)(gs + (wn * 32 + ni * 16 + lr) * LDA + lq * 8);
      bu[ni] = *(const bf16x8*)(us + (wn * 32 + ni * 16 + lr) * LDA + lq * 8);
    }
    #pragma unroll
    for (int mi = 0; mi < 4; ++mi)
      #pragma unroll
      for (int ni = 0; ni < 2; ++ni) {
        accg[mi * 2 + ni] = __builtin_amdgcn_mfma_f32_16x16x32_bf16(
            a[mi], bg[ni], accg[mi * 2 + ni], 0, 0, 0);
        accu[mi * 2 + ni] = __builtin_amdgcn_mfma_f32_16x16x32_bf16(
            a[mi], bu[ni], accu[mi * 2 + ni], 0, 0, 0);
      }
  }

  // epilogue: z = silu(g)*u*wt -> bf16 slot store
  #pragma unroll
  for (int mi = 0; mi < 4; ++mi) {
    #pragma unroll
    for (int ni = 0; ni < 2; ++ni) {
      const int col = ic0 + wn * 32 + ni * 16 + lr;
      f32x4 g = accg[mi * 2 + ni], u = accu[mi * 2 + ni];
      #pragma unroll
      for (int j = 0; j < 4; ++j) {
        const int r = wm * 64 + mi * 16 + lq * 4 + j;
        if (r < nrows) {
          const float gg = g[j];
          const float z = gg / (1.f + __expf(-gg)) * u[j] * s_wt[r];
          zbuf[(size_t)s_slot[r] * INTER + col] = (__bf16)z;
        }
      }
    }
  }
}

// ---------------- Down: out[t,h] += z @ Wd^T (atomic scatter) ---------------
// grid: (expert, token-tile/128, H-chunk/64), block 256 = 4 waves (2x2)
// tile: 128 tokens x 64 H, K=768, BK=32, dbuf LDS, 1 barrier per k-step
__global__ __launch_bounds__(256, 4) void down_kernel(
    const __bf16* __restrict__ zbuf, const float* __restrict__ Wd,
    const int* __restrict__ cnt, const int* __restrict__ elist,
    float* __restrict__ out)
{
  const int e = blockIdx.x;
  const int n_e = cnt[e];
  const int row0 = blockIdx.y * 128;
  if (row0 >= n_e) return;
  const int nrows = min(128, n_e - row0);
  const int hc0 = blockIdx.z * 64;

  __shared__ __bf16 As[2][128 * LDA];
  __shared__ __bf16 Bs[2][64 * LDA];
  __shared__ int s_slot[128];

  const int tid = threadIdx.x;
  if (tid < 128) s_slot[tid] = elist[e * CAP + row0 + min(tid, nrows - 1)];
  __syncthreads();

  // As (z, already bf16): 4 threads per 32-elem row segment, 2 passes
  const int zrow = tid >> 2;          // 0..63 (+64)
  const int zcol = (tid & 3) * 8;     // bf16x8 granularity
  const __bf16* zp0 = zbuf + (size_t)s_slot[zrow] * INTER + zcol;
  const __bf16* zp1 = zbuf + (size_t)s_slot[zrow + 64] * INTER + zcol;
  // Bs (Wd fp32): 8 threads per 32-float row segment, 2 passes
  const int brow = tid >> 3;          // 0..31 (+32)
  const int bcol = (tid & 7) * 4;
  const float* wp0 = Wd + ((size_t)e * HIDDEN + hc0 + brow) * INTER + bcol;
  const float* wp1 = wp0 + (size_t)32 * INTER;

  const int wave = tid >> 6, lane = tid & 63;
  const int wm = wave >> 1, wn = wave & 1;
  const int lq = lane >> 4, lr = lane & 15;

  f32x4 acc[8];
  #pragma unroll
  for (int i = 0; i < 8; ++i) acc[i] = (f32x4){0.f, 0.f, 0.f, 0.f};

  bf16x8 rZ[2];
  float4 rW[2];
  rZ[0] = *(const bf16x8*)(zp0);
  rZ[1] = *(const bf16x8*)(zp1);
  rW[0] = *(const float4*)(wp0);
  rW[1] = *(const float4*)(wp1);

  #pragma unroll 2
  for (int kt = 0; kt < 24; ++kt) {
    __bf16* as = As[kt & 1];
    __bf16* bs = Bs[kt & 1];

    *(bf16x8*)(as + zrow * LDA + zcol) = rZ[0];
    *(bf16x8*)(as + (zrow + 64) * LDA + zcol) = rZ[1];
    {
      bf16x4 b0 = { (__bf16)rW[0].x, (__bf16)rW[0].y, (__bf16)rW[0].z, (__bf16)rW[0].w };
      *(bf16x4*)(bs + brow * LDA + bcol) = b0;
      bf16x4 b1 = { (__bf16)rW[1].x, (__bf16)rW[1].y, (__bf16)rW[1].z, (__bf16)rW[1].w };
      *(bf16x4*)(bs + (brow + 32) * LDA + bcol) = b1;
    }
    __syncthreads();

    if (kt < 23) {
      const int k0 = (kt + 1) * 32;
      rZ[0] = *(const bf16x8*)(zp0 + k0);
      rZ[1] = *(const bf16x8*)(zp1 + k0);
      rW[0] = *(const float4*)(wp0 + k0);
      rW[1] = *(const float4*)(wp1 + k0);
    }

    bf16x8 a[4], b[2];
    #pragma unroll
    for (int mi = 0; mi < 4; ++mi)
      a[mi] = *(const bf16x8*)(as + (wm * 64 + mi * 16 + lr) * LDA + lq * 8);
    #pragma unroll
    for (int ni = 0; ni < 2; ++ni)
      b[ni] = *(const bf16x8*)(bs + (wn * 32 + ni * 16 + lr) * LDA + lq * 8);
    #pragma unroll
    for (int mi = 0; mi < 4; ++mi)
      #pragma unroll
      for (int ni = 0; ni < 2; ++ni)
        acc[mi * 2 + ni] = __builtin_amdgcn_mfma_f32_16x16x32_bf16(
            a[mi], b[ni], acc[mi * 2 + ni], 0, 0, 0);
  }

  #pragma unroll
  for (int mi = 0; mi < 4; ++mi) {
    #pragma unroll
    for (int ni = 0; ni < 2; ++ni) {
      const int h = hc0 + wn * 32 + ni * 16 + lr;
      #pragma unroll
      for (int j = 0; j < 4; ++j) {
        const int r = wm * 64 + mi * 16 + lq * 4 + j;
        if (r < nrows) {
          const int t = s_slot[r] >> 3;
          atomicAdd(out + (size_t)t * HIDDEN + h, acc[mi * 2 + ni][j]);
        }
      }
    }
  }
}

extern "C" void kernel_launch(void* const* d_in, const int* in_sizes, int n_in,
                              void* d_out, int out_size, void* d_ws, size_t ws_size,
                              hipStream_t stream) {
  const float* x  = (const float*)d_in[0];
  const float* gw = (const float*)d_in[1];
  const float* Wg = (const float*)d_in[2];
  const float* Wu = (const float*)d_in[3];
  const float* Wd = (const float*)d_in[4];
  float* out = (float*)d_out;

  char* ws = (char*)d_ws;
  __bf16* zbuf = (__bf16*)ws;                                   // 12,582,912 B
  int*    cnt  = (int*)(ws + 12582912);                         // 256 B
  int*    elist= (int*)(ws + 12582912 + 256);                   // 262,144 B
  float*  ewt  = (float*)(ws + 12582912 + 256 + 262144);        // 262,144 B

  hipMemsetAsync(cnt, 0, NEXP * sizeof(int), stream);
  hipMemsetAsync(out, 0, (size_t)out_size * sizeof(float), stream);

  router_kernel<<<NTOK, 64, 0, stream>>>(x, gw, cnt, elist, ewt);
  gateup_kernel<<<dim3(NEXP, 8, 12), 256, 0, stream>>>(x, Wg, Wu, cnt, elist, ewt, zbuf);
  down_kernel<<<dim3(NEXP, 8, 32), 256, 0, stream>>>(zbuf, Wd, cnt, elist, out);
}